// Round 13
// baseline (232.572 us; speedup 1.0000x reference)
//
#include <hip/hip_runtime.h>
#include <hip/hip_bf16.h>

// Problem constants (match reference)
#define N_NODES 50000
#define N_EDGES 800000
#define HID 128          // HEADS*HEAD_DIM
#define NEG_SLOPE 0.2f
#define BN_EPS 1e-5f

// CSR binning parameters
#define NBLK 256         // blocks over edges
#define BINSZ 512        // nodes per bin (power of 2)
#define BINSH 9
#define NBINS 98         // ceil(N_NODES / BINSZ)

typedef __bf16 v8bf __attribute__((ext_vector_type(8)));
typedef float v4f __attribute__((ext_vector_type(4)));

__device__ __forceinline__ float leaky(float v) {
    return (v > 0.f) ? v : v * NEG_SLOPE;
}
__device__ __forceinline__ unsigned int f2bu(float f) {
    __hip_bfloat16 b = __float2bfloat16(f);
    return (unsigned int)*reinterpret_cast<unsigned short*>(&b);
}
__device__ __forceinline__ unsigned int pack2bf(float lo, float hi) {
    return f2bu(lo) | (f2bu(hi) << 16);
}

// ---------------------------------------------------------------------------
// K_prep_count: fused (independent work):
//   blocks [0, 2*NBLK): per-block LDS histogram of dst bins (rel = bid/NBLK)
//   blocks [2*NBLK, +48): weights -> bf16 conversion
// ---------------------------------------------------------------------------
__global__ __launch_bounds__(256) void k_prep_count(
    const float* __restrict__ w0, const float* __restrict__ w1,
    const float* __restrict__ wsk, unsigned short* __restrict__ wb,
    const int* __restrict__ dst0, const int* __restrict__ dst1,
    int* __restrict__ bincnt) {
    int bid = blockIdx.x;
    if (bid < 2 * NBLK) {
        int rel = bid / NBLK;
        int blk = bid % NBLK;
        const int* dst = rel ? dst1 : dst0;
        __shared__ int cnt[NBINS];
        for (int i = threadIdx.x; i < NBINS; i += 256) cnt[i] = 0;
        __syncthreads();
        const int CH = (N_EDGES + NBLK - 1) / NBLK;   // 3125
        int b0 = blk * CH;
        int b1 = min(N_EDGES, b0 + CH);
        for (int e = b0 + threadIdx.x; e < b1; e += 256)
            atomicAdd(&cnt[dst[e] >> BINSH], 1);
        __syncthreads();
        for (int i = threadIdx.x; i < NBINS; i += 256)
            bincnt[rel * NBINS * NBLK + i * NBLK + blk] = cnt[i];
    } else {
        const int WQ = 128 * 128 / 4;     // 4096 quads per matrix
        int q = (bid - 2 * NBLK) * 256 + threadIdx.x;
        if (q >= 3 * WQ) return;
        int mat = q >> 12;
        int rem = q & 4095;
        const float* W = (mat == 0) ? w0 : (mat == 1) ? w1 : wsk;
        float4 v = ((const float4*)W)[rem];
        ushort4 o;
        o.x = (unsigned short)f2bu(v.x);
        o.y = (unsigned short)f2bu(v.y);
        o.z = (unsigned short)f2bu(v.z);
        o.w = (unsigned short)f2bu(v.w);
        *(ushort4*)(wb + (size_t)mat * 16384 + rem * 4) = o;
    }
}

// ---------------------------------------------------------------------------
// CSR pass B: in-place exclusive scan of bincnt per relation. grid: (2)
// ---------------------------------------------------------------------------
__global__ __launch_bounds__(1024) void k_binscan(int* __restrict__ bincnt) {
    int* a = bincnt + blockIdx.x * NBINS * NBLK;
    const int TOT = NBINS * NBLK;                 // 25088
    const int CH = (TOT + 1023) / 1024;           // 25
    int tid = threadIdx.x;
    int base = tid * CH;
    int lv[CH];
    int sum = 0;
    for (int i = 0; i < CH; i++) {
        int idx = base + i;
        int v = (idx < TOT) ? a[idx] : 0;
        lv[i] = sum;
        sum += v;
    }
    __shared__ int ls[1024];
    ls[tid] = sum;
    __syncthreads();
    for (int ofs = 1; ofs < 1024; ofs <<= 1) {
        int v = (tid >= ofs) ? ls[tid - ofs] : 0;
        __syncthreads();
        ls[tid] += v;
        __syncthreads();
    }
    int pre = tid ? ls[tid - 1] : 0;
    for (int i = 0; i < CH; i++) {
        int idx = base + i;
        if (idx < TOT) a[idx] = pre + lv[i];
    }
}

// ---------------------------------------------------------------------------
// CSR pass C: scatter packed (dst_local|src<<9, ew) 8B pairs into
// per-(bin,block) contiguous runs. grid: (NBLK, 2)
// ---------------------------------------------------------------------------
__global__ __launch_bounds__(256) void k_binscatter(const int* __restrict__ dst0,
                                                    const int* __restrict__ dst1,
                                                    const int* __restrict__ src0,
                                                    const int* __restrict__ src1,
                                                    const float* __restrict__ ew0,
                                                    const float* __restrict__ ew1,
                                                    const int* __restrict__ bincnt,
                                                    int2* __restrict__ pairs0,
                                                    int2* __restrict__ pairs1) {
    int rel = blockIdx.y;
    const int* dst = rel ? dst1 : dst0;
    const int* src = rel ? src1 : src0;
    const float* ew = rel ? ew1 : ew0;
    int2* pairs = rel ? pairs1 : pairs0;
    __shared__ int cur[NBINS];
    for (int i = threadIdx.x; i < NBINS; i += 256)
        cur[i] = bincnt[rel * NBINS * NBLK + i * NBLK + blockIdx.x];
    __syncthreads();
    const int CH = (N_EDGES + NBLK - 1) / NBLK;
    int b0 = blockIdx.x * CH;
    int b1 = min(N_EDGES, b0 + CH);
    for (int e = b0 + threadIdx.x; e < b1; e += 256) {
        int d = dst[e];
        int pos = atomicAdd(&cur[d >> BINSH], 1);
        unsigned int packed = (unsigned int)(d & (BINSZ - 1)) |
                              ((unsigned int)src[e] << BINSH);
        pairs[pos] = make_int2((int)packed, __float_as_int(ew[e]));
    }
}

// ---------------------------------------------------------------------------
// CSR pass D: per (rel,bin): LDS histogram -> scan -> offs (+sentinel) ->
// place 8B records (srcByteOff, bf16 (ex*ew) pair) sorted by dst, AND
// accumulate den[node][head] = sum(ex) in f32 LDS -> den2 table.
// grid: (NBINS, 2)
// ---------------------------------------------------------------------------
__global__ __launch_bounds__(256) void k_csr(const int* __restrict__ bincnt,
                                             const int2* __restrict__ pairs0,
                                             const int2* __restrict__ pairs1,
                                             const float* __restrict__ el0,
                                             const float* __restrict__ er0,
                                             const float* __restrict__ el1,
                                             const float* __restrict__ er1,
                                             int* __restrict__ offs0,
                                             int* __restrict__ offs1,
                                             int2* __restrict__ rec0,
                                             int2* __restrict__ rec1,
                                             float2* __restrict__ den20,
                                             float2* __restrict__ den21) {
    int rel = blockIdx.y;
    const int2* pairs = rel ? pairs1 : pairs0;
    const float* el = rel ? el1 : el0;
    const float* er = rel ? er1 : er0;
    int* offs = rel ? offs1 : offs0;
    int2* rec = rel ? rec1 : rec0;
    float2* den2 = rel ? den21 : den20;
    int bin = blockIdx.x;
    int tid = threadIdx.x;
    const int* bc = bincnt + rel * NBINS * NBLK;
    int pbase = bc[bin * NBLK];
    int pend = (bin < NBINS - 1) ? bc[(bin + 1) * NBLK] : N_EDGES;
    int n0 = bin << BINSH;
    int nn = min(N_NODES - n0, BINSZ);

    __shared__ int s_deg[BINSZ];
    __shared__ int s_ts[256];
    __shared__ float sden[BINSZ * 2];
    for (int i = tid; i < BINSZ; i += 256) s_deg[i] = 0;
    for (int i = tid; i < BINSZ * 2; i += 256) sden[i] = 0.f;
    __syncthreads();
    for (int p = pbase + tid; p < pend; p += 256)
        atomicAdd(&s_deg[((unsigned int)pairs[p].x) & (BINSZ - 1)], 1);
    __syncthreads();

    int d0 = s_deg[tid * 2], d1 = s_deg[tid * 2 + 1];
    s_ts[tid] = d0 + d1;
    __syncthreads();
    for (int ofs = 1; ofs < 256; ofs <<= 1) {
        int v = (tid >= ofs) ? s_ts[tid - ofs] : 0;
        __syncthreads();
        s_ts[tid] += v;
        __syncthreads();
    }
    int pre = tid ? s_ts[tid - 1] : 0;
    s_deg[tid * 2] = pbase + pre;
    s_deg[tid * 2 + 1] = pbase + pre + d0;
    __syncthreads();

    for (int l = tid; l < nn; l += 256) offs[n0 + l] = s_deg[l];
    if (bin == NBINS - 1 && tid == 0) offs[N_NODES] = N_EDGES;
    __syncthreads();

    for (int p = pbase + tid; p < pend; p += 256) {
        int2 pr = pairs[p];
        unsigned int u = (unsigned int)pr.x;
        int dl = (int)(u & (BINSZ - 1));
        int s = (int)(u >> BINSH);
        int pos = atomicAdd(&s_deg[dl], 1);
        float2 ev = *(const float2*)(el + 2 * s);
        float2 rv = *(const float2*)(er + 2 * (n0 + dl));
        float x0 = expf(leaky(ev.x + rv.x));
        float x1 = expf(leaky(ev.y + rv.y));
        atomicAdd(&sden[dl * 2], x0);
        atomicAdd(&sden[dl * 2 + 1], x1);
        float ew = __int_as_float(pr.y);
        rec[pos] = make_int2(s << 8, (int)pack2bf(x0 * ew, x1 * ew));
    }
    __syncthreads();
    for (int l = tid; l < nn; l += 256)
        den2[n0 + l] = make_float2(sden[l * 2], sden[l * 2 + 1]);
}

// ---------------------------------------------------------------------------
// K1: MFMA GEMM, full-width B staging: 3 stages (one per weight matrix,
// 128x128 bf16 = 32 KB), 6 barriers/block total (was 12). Swapped operands:
// D[col][node] -> vectorized epilogue. grid (782), 4 waves.
// ---------------------------------------------------------------------------
__global__ __launch_bounds__(256) void k_gemm_mfma(
    const float* __restrict__ x, const unsigned short* __restrict__ wb,
    const float* __restrict__ skip_b,
    const float* __restrict__ al0, const float* __restrict__ ar0,
    const float* __restrict__ al1, const float* __restrict__ ar1,
    unsigned short* __restrict__ fb0, unsigned short* __restrict__ fb1,
    float* __restrict__ el0, float* __restrict__ er0,
    float* __restrict__ el1, float* __restrict__ er1,
    float* __restrict__ hs) {
    __shared__ unsigned short As[64][128];    // 16 KB
    __shared__ unsigned short Bs[128][128];   // 32 KB
    int tid = threadIdx.x;
    int m0 = blockIdx.x * 64;

    // stage A once from f32, convert, XOR-swizzle on 16B granules
#pragma unroll
    for (int i = 0; i < 4; i++) {
        int idx = tid * 4 + i;
        int row = idx >> 4, seg = idx & 15;
        int gr = m0 + row;
        uint4 o = make_uint4(0, 0, 0, 0);
        if (gr < N_NODES) {
            const float* p = x + (size_t)gr * HID + seg * 8;
            float4 p0 = *(const float4*)p;
            float4 p1 = *(const float4*)(p + 4);
            o.x = pack2bf(p0.x, p0.y);
            o.y = pack2bf(p0.z, p0.w);
            o.z = pack2bf(p1.x, p1.y);
            o.w = pack2bf(p1.z, p1.w);
        }
        *(uint4*)(&As[row][(seg ^ (row & 7)) * 8]) = o;
    }
    __syncthreads();

    int w = tid >> 6, l = tid & 63;
    int lr = l & 15, lg = l >> 4;
    int node = m0 + w * 16 + lr;
    bool valid = node < N_NODES;
    int arow = w * 16 + lr;
    v8bf afrag[4];
#pragma unroll
    for (int kb = 0; kb < 4; kb++)
        afrag[kb] = *(v8bf*)(&As[arow][((kb * 4 + lg) ^ (arow & 7)) * 8]);

    for (int mat = 0; mat < 3; mat++) {
        const unsigned short* wmat = wb + (size_t)mat * 16384;
        __syncthreads();                  // prior mat's Bs reads complete
#pragma unroll
        for (int i = 0; i < 8; i++) {
            int idx = tid * 8 + i;        // 0..2047
            int row = idx >> 4, seg = idx & 15;
            uint4 wv = *(const uint4*)(wmat + row * HID + seg * 8);
            *(uint4*)(&Bs[row][(seg ^ (row & 7)) * 8]) = wv;
        }
        __syncthreads();

        // SWAPPED: acc[nt] = W_frag x X_frag -> D[col][node]
        // lane (lr,lg) holds cols nt*16+lg*4+r (r=0..3) of node `node`
        v4f acc[8] = {};
#pragma unroll
        for (int nt = 0; nt < 8; nt++) {
            int brow = nt * 16 + lr;
#pragma unroll
            for (int kb = 0; kb < 4; kb++) {
                v8bf bfrag =
                    *(v8bf*)(&Bs[brow][((kb * 4 + lg) ^ (brow & 7)) * 8]);
                acc[nt] = __builtin_amdgcn_mfma_f32_16x16x32_bf16(
                    bfrag, afrag[kb], acc[nt], 0, 0, 0);
            }
        }

        if (mat < 2) {
            const float* al = mat ? al1 : al0;
            const float* ar = mat ? ar1 : ar0;
            float* elp = mat ? el1 : el0;
            float* erp = mat ? er1 : er0;
            unsigned short* fbp = mat ? fb1 : fb0;
            // per-head attention dots: head = nt>>2 (cols 0-63 h0, 64-127 h1)
            float elv0 = 0.f, erv0 = 0.f, elv1 = 0.f, erv1 = 0.f;
#pragma unroll
            for (int nt = 0; nt < 8; nt++) {
                int c0 = nt * 16 + lg * 4;
                float4 av = *(const float4*)(al + c0);
                float4 rv = *(const float4*)(ar + c0);
                float e = acc[nt][0] * av.x + acc[nt][1] * av.y +
                          acc[nt][2] * av.z + acc[nt][3] * av.w;
                float r = acc[nt][0] * rv.x + acc[nt][1] * rv.y +
                          acc[nt][2] * rv.z + acc[nt][3] * rv.w;
                if (nt < 4) { elv0 += e; erv0 += r; }
                else        { elv1 += e; erv1 += r; }
            }
            elv0 += __shfl_xor(elv0, 16);
            elv0 += __shfl_xor(elv0, 32);
            erv0 += __shfl_xor(erv0, 16);
            erv0 += __shfl_xor(erv0, 32);
            elv1 += __shfl_xor(elv1, 16);
            elv1 += __shfl_xor(elv1, 32);
            erv1 += __shfl_xor(erv1, 16);
            erv1 += __shfl_xor(erv1, 32);
            if (valid) {
#pragma unroll
                for (int nt = 0; nt < 8; nt++) {
                    uint2 o;
                    o.x = pack2bf(acc[nt][0], acc[nt][1]);
                    o.y = pack2bf(acc[nt][2], acc[nt][3]);
                    *(uint2*)(fbp + (size_t)node * HID + nt * 16 + lg * 4) = o;
                }
                if (lg == 0) {
                    elp[node * 2 + 0] = elv0;
                    erp[node * 2 + 0] = erv0;
                    elp[node * 2 + 1] = elv1;
                    erp[node * 2 + 1] = erv1;
                }
            }
        } else if (valid) {
#pragma unroll
            for (int nt = 0; nt < 8; nt++) {
                int c0 = nt * 16 + lg * 4;
                float4 sb = *(const float4*)(skip_b + c0);
                float4 o;
                o.x = acc[nt][0] + sb.x;
                o.y = acc[nt][1] + sb.y;
                o.z = acc[nt][2] + sb.z;
                o.w = acc[nt][3] + sb.w;
                *(float4*)(hs + (size_t)node * HID + c0) = o;
            }
        }
    }
}

// ---------------------------------------------------------------------------
// K_aggregate: wave per dst node, single pass (den precomputed). 4 edges in
// flight, 16 lanes/edge, unroll 4 for deeper MLP. h updated in place.
// ---------------------------------------------------------------------------
__device__ __forceinline__ void agg_rel2(const int* __restrict__ offs,
                                         const int2* __restrict__ rec,
                                         const float2* __restrict__ den2,
                                         const unsigned char* __restrict__ fbb,
                                         int n, int lane, int sub,
                                         int hh, float* a) {
    int b = offs[n];
    int e_end = offs[n + 1];
    int deg = e_end - b;
    if (deg <= 0) return;
    float2 dn = den2[n];
    float inv0 = 1.f / dn.x, inv1 = 1.f / dn.y;

    int nchunk = (deg + 63) >> 6;
    for (int ch = 0; ch < nchunk; ch++) {
        int p = b + (ch << 6) + lane;
        int s = 0;
        unsigned int wpk = 0;
        if (p < e_end) {
            int2 r = rec[p];
            s = r.x;
            wpk = (unsigned int)r.y;
        }
        unsigned int pk = pack2bf(__uint_as_float(wpk << 16) * inv0,
                                  __uint_as_float(wpk & 0xffff0000u) * inv1);
        int cnt = deg - (ch << 6);
        if (cnt > 64) cnt = 64;
        int ng = (cnt + 3) >> 2;
#pragma unroll 4
        for (int g = 0; g < ng; g++) {
            int sl = (g << 2) + sub;
            int sj = __shfl(s, sl);                      // byte offset
            unsigned int pkj = (unsigned int)__shfl((int)pk, sl);
            float aj = __uint_as_float(hh ? (pkj & 0xffff0000u) : (pkj << 16));
            uint4 fv = *(const uint4*)(fbb + sj);
            a[0] += aj * __uint_as_float(fv.x << 16);
            a[1] += aj * __uint_as_float(fv.x & 0xffff0000u);
            a[2] += aj * __uint_as_float(fv.y << 16);
            a[3] += aj * __uint_as_float(fv.y & 0xffff0000u);
            a[4] += aj * __uint_as_float(fv.z << 16);
            a[5] += aj * __uint_as_float(fv.z & 0xffff0000u);
            a[6] += aj * __uint_as_float(fv.w << 16);
            a[7] += aj * __uint_as_float(fv.w & 0xffff0000u);
        }
    }
}

__global__ __launch_bounds__(256) void k_aggregate(
    const int* __restrict__ offs0, const int2* __restrict__ rec0,
    const float2* __restrict__ den20, const unsigned short* __restrict__ fb0,
    const int* __restrict__ offs1, const int2* __restrict__ rec1,
    const float2* __restrict__ den21, const unsigned short* __restrict__ fb1,
    const float* __restrict__ bias0, const float* __restrict__ bias1,
    float* __restrict__ h) {
    int wave = threadIdx.x >> 6, lane = threadIdx.x & 63;
    int n = blockIdx.x * 4 + wave;
    if (n >= N_NODES) return;
    int cb = lane & 15;        // col block: cols cb*8 .. cb*8+7
    int sub = lane >> 4;       // sub-edge slot (4 edges in flight)
    int hh = cb >> 3;          // head of these cols
    float a[8] = {0.f, 0.f, 0.f, 0.f, 0.f, 0.f, 0.f, 0.f};
    const unsigned char* fbb0 = (const unsigned char*)fb0 + cb * 16;
    const unsigned char* fbb1 = (const unsigned char*)fb1 + cb * 16;
    agg_rel2(offs0, rec0, den20, fbb0, n, lane, sub, hh, a);
    agg_rel2(offs1, rec1, den21, fbb1, n, lane, sub, hh, a);
#pragma unroll
    for (int j = 0; j < 8; j++) {
        a[j] += __shfl_xor(a[j], 16);
        a[j] += __shfl_xor(a[j], 32);
    }
    if (sub == 0) {
        size_t base = (size_t)n * HID + cb * 8;
        float4 v0 = *(const float4*)(h + base);
        float4 v1 = *(const float4*)(h + base + 4);
        int c0 = cb * 8;
        float4 o0, o1;
        o0.x = v0.x + fmaxf(a[0] + bias0[c0 + 0] + bias1[c0 + 0], 0.f);
        o0.y = v0.y + fmaxf(a[1] + bias0[c0 + 1] + bias1[c0 + 1], 0.f);
        o0.z = v0.z + fmaxf(a[2] + bias0[c0 + 2] + bias1[c0 + 2], 0.f);
        o0.w = v0.w + fmaxf(a[3] + bias0[c0 + 3] + bias1[c0 + 3], 0.f);
        o1.x = v1.x + fmaxf(a[4] + bias0[c0 + 4] + bias1[c0 + 4], 0.f);
        o1.y = v1.y + fmaxf(a[5] + bias0[c0 + 5] + bias1[c0 + 5], 0.f);
        o1.z = v1.z + fmaxf(a[6] + bias0[c0 + 6] + bias1[c0 + 6], 0.f);
        o1.w = v1.w + fmaxf(a[7] + bias0[c0 + 7] + bias1[c0 + 7], 0.f);
        *(float4*)(h + base) = o0;
        *(float4*)(h + base + 4) = o1;
    }
}

// ---------------------------------------------------------------------------
// K_bnstats: per-column partial sums over h (float4 loads).
// EXACTLY 512 blocks x 256 threads.
// ---------------------------------------------------------------------------
__global__ __launch_bounds__(256) void k_bnstats(const float* __restrict__ h,
                                                 double* __restrict__ psum,
                                                 double* __restrict__ psumsq) {
    int tid = threadIdx.x;
    const float4* h4 = (const float4*)h;
    double s[4] = {0.0, 0.0, 0.0, 0.0};
    double q[4] = {0.0, 0.0, 0.0, 0.0};
    const int totalv = N_NODES * HID / 4;         // 1.6M float4s
    const int stride = 512 * 256;                 // multiple of 32: cols fixed
    for (int i = blockIdx.x * 256 + tid; i < totalv; i += stride) {
        float4 v = h4[i];
        s[0] += v.x; q[0] += (double)v.x * v.x;
        s[1] += v.y; q[1] += (double)v.y * v.y;
        s[2] += v.z; q[2] += (double)v.z * v.z;
        s[3] += v.w; q[3] += (double)v.w * v.w;
    }
    __shared__ double ls[256][4], lq[256][4];
#pragma unroll
    for (int j = 0; j < 4; j++) {
        ls[tid][j] = s[j];
        lq[tid][j] = q[j];
    }
    __syncthreads();
    if (tid < 32) {                                // col quad = tid*4 + j
#pragma unroll
        for (int j = 0; j < 4; j++) {
            double ss = 0.0, qq = 0.0;
            for (int t = tid; t < 256; t += 32) {
                ss += ls[t][j];
                qq += lq[t][j];
            }
            psum[blockIdx.x * 128 + tid * 4 + j] = ss;
            psumsq[blockIdx.x * 128 + tid * 4 + j] = qq;
        }
    }
}

__global__ void k_bn_finalize(const double* __restrict__ psum,
                              const double* __restrict__ psumsq,
                              const float* __restrict__ gamma,
                              const float* __restrict__ beta,
                              float* __restrict__ ss) {
    int c = threadIdx.x;
    double s = 0.0, q = 0.0;
    for (int b = 0; b < 512; b++) {
        s += psum[b * 128 + c];
        q += psumsq[b * 128 + c];
    }
    double mu = s / N_NODES;
    double var = q / N_NODES - mu * mu;
    float sc = gamma[c] * (float)(1.0 / sqrt(var + (double)BN_EPS));
    ss[c] = sc;
    ss[128 + c] = beta[c] - (float)mu * sc;
}

// ---------------------------------------------------------------------------
// K_classify: MFMA 16x16x32, swapped: D[class][node]; lane holds 4 consecutive
// classes of one node -> single float4 store. grid 782 x 4 waves.
// ---------------------------------------------------------------------------
__global__ __launch_bounds__(256) void k_classify(const float* __restrict__ h,
                                                  const float* __restrict__ ss,
                                                  const float* __restrict__ clf_w,
                                                  const float* __restrict__ clf_b,
                                                  float* __restrict__ out) {
    int w = threadIdx.x >> 6, l = threadIdx.x & 63;
    int lr = l & 15, lg = l >> 4;
    int n0 = (blockIdx.x * 4 + w) * 16;
    if (n0 >= N_NODES) return;

    v8bf afrag[4], bfrag[4];
#pragma unroll
    for (int kb = 0; kb < 4; kb++) {
        int k0 = kb * 32 + lg * 8;
        const float* bp = clf_w + lr * HID + k0;    // class lr weights
        float4 b0 = *(const float4*)bp;
        float4 b1 = *(const float4*)(bp + 4);
        bfrag[kb][0] = (__bf16)b0.x; bfrag[kb][1] = (__bf16)b0.y;
        bfrag[kb][2] = (__bf16)b0.z; bfrag[kb][3] = (__bf16)b0.w;
        bfrag[kb][4] = (__bf16)b1.x; bfrag[kb][5] = (__bf16)b1.y;
        bfrag[kb][6] = (__bf16)b1.z; bfrag[kb][7] = (__bf16)b1.w;
        const float* ap = h + (size_t)(n0 + lr) * HID + k0;  // node lr
        float4 a0 = *(const float4*)ap;
        float4 a1 = *(const float4*)(ap + 4);
        float4 sc0 = *(const float4*)(ss + k0);
        float4 sc1 = *(const float4*)(ss + k0 + 4);
        float4 sh0 = *(const float4*)(ss + 128 + k0);
        float4 sh1 = *(const float4*)(ss + 128 + k0 + 4);
        afrag[kb][0] = (__bf16)fmaxf(a0.x * sc0.x + sh0.x, 0.f);
        afrag[kb][1] = (__bf16)fmaxf(a0.y * sc0.y + sh0.y, 0.f);
        afrag[kb][2] = (__bf16)fmaxf(a0.z * sc0.z + sh0.z, 0.f);
        afrag[kb][3] = (__bf16)fmaxf(a0.w * sc0.w + sh0.w, 0.f);
        afrag[kb][4] = (__bf16)fmaxf(a1.x * sc1.x + sh1.x, 0.f);
        afrag[kb][5] = (__bf16)fmaxf(a1.y * sc1.y + sh1.y, 0.f);
        afrag[kb][6] = (__bf16)fmaxf(a1.z * sc1.z + sh1.z, 0.f);
        afrag[kb][7] = (__bf16)fmaxf(a1.w * sc1.w + sh1.w, 0.f);
    }
    // SWAPPED: D[class][node]; lane holds classes lg*4+r of node n0+lr
    v4f acc = {};
#pragma unroll
    for (int kb = 0; kb < 4; kb++)
        acc = __builtin_amdgcn_mfma_f32_16x16x32_bf16(bfrag[kb], afrag[kb],
                                                      acc, 0, 0, 0);
    float4 cb = *(const float4*)(clf_b + lg * 4);
    float4 o;
    o.x = acc[0] + cb.x;
    o.y = acc[1] + cb.y;
    o.z = acc[2] + cb.z;
    o.w = acc[3] + cb.w;
    *(float4*)(out + (size_t)(n0 + lr) * 16 + lg * 4) = o;
}

// ---------------------------------------------------------------------------
extern "C" void kernel_launch(void* const* d_in, const int* in_sizes, int n_in,
                              void* d_out, int out_size, void* d_ws, size_t ws_size,
                              hipStream_t stream) {
    (void)in_sizes; (void)n_in; (void)out_size; (void)ws_size;
    const float* x      = (const float*)d_in[0];
    const int*   src0   = (const int*)d_in[1];
    const int*   dst0   = (const int*)d_in[2];
    const float* ew0    = (const float*)d_in[3];
    const int*   src1   = (const int*)d_in[4];
    const int*   dst1   = (const int*)d_in[5];
    const float* ew1    = (const float*)d_in[6];
    const float* fc_w0  = (const float*)d_in[7];
    const float* bias0  = (const float*)d_in[8];
    const float* al0    = (const float*)d_in[9];
    const float* ar0    = (const float*)d_in[10];
    const float* fc_w1  = (const float*)d_in[11];
    const float* bias1  = (const float*)d_in[12];
    const float* al1    = (const float*)d_in[13];
    const float* ar1    = (const float*)d_in[14];
    const float* skip_w = (const float*)d_in[15];
    const float* skip_b = (const float*)d_in[16];
    const float* gamma  = (const float*)d_in[17];
    const float* beta   = (const float*)d_in[18];
    const float* clf_w  = (const float*)d_in[19];
    const float* clf_b  = (const float*)d_in[20];
    float* out = (float*)d_out;

    char* wsp = (char*)d_ws;
    size_t off = 0;
    auto alloc = [&](size_t bytes) -> char* {
        char* p = wsp + off;
        off += (bytes + 255) & ~(size_t)255;
        return p;
    };
    unsigned short* wbf = (unsigned short*)alloc((size_t)3 * 16384 * 2);
    unsigned short* fb0 = (unsigned short*)alloc((size_t)N_NODES * HID * 2);
    unsigned short* fb1 = (unsigned short*)alloc((size_t)N_NODES * HID * 2);
    float*  hs     = (float*)alloc((size_t)N_NODES * HID * 4);   // becomes h
    float*  el0    = (float*)alloc((size_t)N_NODES * 2 * 4);
    float*  er0    = (float*)alloc((size_t)N_NODES * 2 * 4);
    float*  el1    = (float*)alloc((size_t)N_NODES * 2 * 4);
    float*  er1    = (float*)alloc((size_t)N_NODES * 2 * 4);
    int*    bincnt = (int*)alloc((size_t)2 * NBINS * NBLK * 4);
    int2*   pairs0 = (int2*)alloc((size_t)N_EDGES * 8);
    int2*   pairs1 = (int2*)alloc((size_t)N_EDGES * 8);
    int*    offs0  = (int*)alloc((size_t)(N_NODES + 1) * 4);
    int*    offs1  = (int*)alloc((size_t)(N_NODES + 1) * 4);
    int2*   rec0   = (int2*)alloc((size_t)N_EDGES * 8);
    int2*   rec1   = (int2*)alloc((size_t)N_EDGES * 8);
    float2* den20  = (float2*)alloc((size_t)N_NODES * 8);
    float2* den21  = (float2*)alloc((size_t)N_NODES * 8);
    double* psum   = (double*)alloc((size_t)512 * 128 * 8);
    double* psumsq = (double*)alloc((size_t)512 * 128 * 8);
    float*  ss     = (float*)alloc(256 * 4);

    // fused: dst-bin histogram (512 blocks) + weight bf16 conversion (48)
    k_prep_count<<<2 * NBLK + 48, 256, 0, stream>>>(fc_w0, fc_w1, skip_w, wbf,
                                                    dst0, dst1, bincnt);
    k_binscan<<<2, 1024, 0, stream>>>(bincnt);
    dim3 gbin(NBLK, 2);
    k_binscatter<<<gbin, 256, 0, stream>>>(dst0, dst1, src0, src1, ew0, ew1,
                                           bincnt, pairs0, pairs1);

    // MFMA GEMM (full-width B staging, 6 barriers) + dots + hs
    k_gemm_mfma<<<(N_NODES + 63) / 64, 256, 0, stream>>>(
        x, wbf, skip_b, al0, ar0, al1, ar1,
        fb0, fb1, el0, er0, el1, er1, hs);

    // CSR finalize: 8B records (ex*ew bf16) + f32 per-node denominators
    dim3 gcsr(NBINS, 2);
    k_csr<<<gcsr, 256, 0, stream>>>(bincnt, pairs0, pairs1,
                                    el0, er0, el1, er1,
                                    offs0, offs1, rec0, rec1, den20, den21);

    // gather aggregation (single pass), h = hs + relu(bias + msgs) in place
    k_aggregate<<<(N_NODES + 3) / 4, 256, 0, stream>>>(
        offs0, rec0, den20, fb0, offs1, rec1, den21, fb1, bias0, bias1, hs);

    k_bnstats<<<512, 256, 0, stream>>>(hs, psum, psumsq);
    k_bn_finalize<<<1, 128, 0, stream>>>(psum, psumsq, gamma, beta, ss);
    k_classify<<<(N_NODES + 63) / 64, 256, 0, stream>>>(
        hs, ss, clf_w, clf_b, out);
}

// Round 14
// 218.987 us; speedup vs baseline: 1.0620x; 1.0620x over previous
//
#include <hip/hip_runtime.h>
#include <hip/hip_bf16.h>

// Problem constants (match reference)
#define N_NODES 50000
#define N_EDGES 800000
#define HID 128          // HEADS*HEAD_DIM
#define NEG_SLOPE 0.2f
#define BN_EPS 1e-5f

// CSR binning parameters
#define NBLK 256         // blocks over edges
#define BINSZ 512        // nodes per bin (power of 2)
#define BINSH 9
#define NBINS 98         // ceil(N_NODES / BINSZ)

#define GEMM_BLOCKS ((N_NODES + 63) / 64)   // 782

typedef __bf16 v8bf __attribute__((ext_vector_type(8)));
typedef float v4f __attribute__((ext_vector_type(4)));

__device__ __forceinline__ float leaky(float v) {
    return (v > 0.f) ? v : v * NEG_SLOPE;
}
__device__ __forceinline__ unsigned int f2bu(float f) {
    __hip_bfloat16 b = __float2bfloat16(f);
    return (unsigned int)*reinterpret_cast<unsigned short*>(&b);
}
__device__ __forceinline__ unsigned int pack2bf(float lo, float hi) {
    return f2bu(lo) | (f2bu(hi) << 16);
}

// ---------------------------------------------------------------------------
// K_prep_count: fused (independent work):
//   blocks [0, 2*NBLK): per-block LDS histogram of dst bins (rel = bid/NBLK)
//   blocks [2*NBLK, +48): weights -> bf16 conversion
// ---------------------------------------------------------------------------
__global__ __launch_bounds__(256) void k_prep_count(
    const float* __restrict__ w0, const float* __restrict__ w1,
    const float* __restrict__ wsk, unsigned short* __restrict__ wb,
    const int* __restrict__ dst0, const int* __restrict__ dst1,
    int* __restrict__ bincnt) {
    int bid = blockIdx.x;
    if (bid < 2 * NBLK) {
        int rel = bid / NBLK;
        int blk = bid % NBLK;
        const int* dst = rel ? dst1 : dst0;
        __shared__ int cnt[NBINS];
        for (int i = threadIdx.x; i < NBINS; i += 256) cnt[i] = 0;
        __syncthreads();
        const int CH = (N_EDGES + NBLK - 1) / NBLK;   // 3125
        int b0 = blk * CH;
        int b1 = min(N_EDGES, b0 + CH);
        for (int e = b0 + threadIdx.x; e < b1; e += 256)
            atomicAdd(&cnt[dst[e] >> BINSH], 1);
        __syncthreads();
        for (int i = threadIdx.x; i < NBINS; i += 256)
            bincnt[rel * NBINS * NBLK + i * NBLK + blk] = cnt[i];
    } else {
        const int WQ = 128 * 128 / 4;     // 4096 quads per matrix
        int q = (bid - 2 * NBLK) * 256 + threadIdx.x;
        if (q >= 3 * WQ) return;
        int mat = q >> 12;
        int rem = q & 4095;
        const float* W = (mat == 0) ? w0 : (mat == 1) ? w1 : wsk;
        float4 v = ((const float4*)W)[rem];
        ushort4 o;
        o.x = (unsigned short)f2bu(v.x);
        o.y = (unsigned short)f2bu(v.y);
        o.z = (unsigned short)f2bu(v.z);
        o.w = (unsigned short)f2bu(v.w);
        *(ushort4*)(wb + (size_t)mat * 16384 + rem * 4) = o;
    }
}

// ---------------------------------------------------------------------------
// CSR pass B: in-place exclusive scan of bincnt per relation. grid: (2)
// ---------------------------------------------------------------------------
__global__ __launch_bounds__(1024) void k_binscan(int* __restrict__ bincnt) {
    int* a = bincnt + blockIdx.x * NBINS * NBLK;
    const int TOT = NBINS * NBLK;                 // 25088
    const int CH = (TOT + 1023) / 1024;           // 25
    int tid = threadIdx.x;
    int base = tid * CH;
    int lv[CH];
    int sum = 0;
    for (int i = 0; i < CH; i++) {
        int idx = base + i;
        int v = (idx < TOT) ? a[idx] : 0;
        lv[i] = sum;
        sum += v;
    }
    __shared__ int ls[1024];
    ls[tid] = sum;
    __syncthreads();
    for (int ofs = 1; ofs < 1024; ofs <<= 1) {
        int v = (tid >= ofs) ? ls[tid - ofs] : 0;
        __syncthreads();
        ls[tid] += v;
        __syncthreads();
    }
    int pre = tid ? ls[tid - 1] : 0;
    for (int i = 0; i < CH; i++) {
        int idx = base + i;
        if (idx < TOT) a[idx] = pre + lv[i];
    }
}

// ---------------------------------------------------------------------------
// K_scatter_gemm: heterogeneous fusion of two INDEPENDENT stages:
//   blocks [0, 2*NBLK): CSR pass C — scatter packed (dst_local|src<<9, ew)
//       8B pairs into per-(bin,block) contiguous runs.
//   blocks [2*NBLK, +GEMM_BLOCKS): MFMA GEMM (round-12 structure):
//       A staged once (f32->bf16, XOR-swizzled); B staged per (mat,half)
//       slice from bf16 weights; swapped operands -> D[col][node];
//       vectorized epilogue; fused attention dots; hs + skip_b.
// Both must complete before k_csr; fusing converts scatter time to overlap.
// ---------------------------------------------------------------------------
__global__ __launch_bounds__(256) void k_scatter_gemm(
    // scatter args
    const int* __restrict__ dst0, const int* __restrict__ dst1,
    const int* __restrict__ src0, const int* __restrict__ src1,
    const float* __restrict__ ew0, const float* __restrict__ ew1,
    const int* __restrict__ bincnt,
    int2* __restrict__ pairs0, int2* __restrict__ pairs1,
    // gemm args
    const float* __restrict__ x, const unsigned short* __restrict__ wb,
    const float* __restrict__ skip_b,
    const float* __restrict__ al0, const float* __restrict__ ar0,
    const float* __restrict__ al1, const float* __restrict__ ar1,
    unsigned short* __restrict__ fb0, unsigned short* __restrict__ fb1,
    float* __restrict__ el0, float* __restrict__ er0,
    float* __restrict__ el1, float* __restrict__ er1,
    float* __restrict__ hs) {
    __shared__ unsigned short As[64][128];   // 16 KB (scatter reuses as cur[])
    __shared__ unsigned short Bs[64][128];   // 16 KB
    int tid = threadIdx.x;
    int bid = blockIdx.x;

    if (bid < 2 * NBLK) {
        // ----- CSR pass C: binscatter -----
        int rel = bid >> 8;                  // NBLK == 256
        int blk = bid & (NBLK - 1);
        const int* dst = rel ? dst1 : dst0;
        const int* src = rel ? src1 : src0;
        const float* ew = rel ? ew1 : ew0;
        int2* pairs = rel ? pairs1 : pairs0;
        int* cur = (int*)&As[0][0];
        for (int i = tid; i < NBINS; i += 256)
            cur[i] = bincnt[rel * NBINS * NBLK + i * NBLK + blk];
        __syncthreads();
        const int CH = (N_EDGES + NBLK - 1) / NBLK;
        int b0 = blk * CH;
        int b1 = min(N_EDGES, b0 + CH);
        for (int e = b0 + tid; e < b1; e += 256) {
            int d = dst[e];
            int pos = atomicAdd(&cur[d >> BINSH], 1);
            unsigned int packed = (unsigned int)(d & (BINSZ - 1)) |
                                  ((unsigned int)src[e] << BINSH);
            pairs[pos] = make_int2((int)packed, __float_as_int(ew[e]));
        }
        return;
    }

    // ----- MFMA GEMM -----
    int m0 = (bid - 2 * NBLK) * 64;

    // stage A once from f32, convert, XOR-swizzle on 16B granules
#pragma unroll
    for (int i = 0; i < 4; i++) {
        int idx = tid * 4 + i;
        int row = idx >> 4, seg = idx & 15;
        int gr = m0 + row;
        uint4 o = make_uint4(0, 0, 0, 0);
        if (gr < N_NODES) {
            const float* p = x + (size_t)gr * HID + seg * 8;
            float4 p0 = *(const float4*)p;
            float4 p1 = *(const float4*)(p + 4);
            o.x = pack2bf(p0.x, p0.y);
            o.y = pack2bf(p0.z, p0.w);
            o.z = pack2bf(p1.x, p1.y);
            o.w = pack2bf(p1.z, p1.w);
        }
        *(uint4*)(&As[row][(seg ^ (row & 7)) * 8]) = o;
    }
    __syncthreads();

    int w = tid >> 6, l = tid & 63;
    int lr = l & 15, lg = l >> 4;
    int node = m0 + w * 16 + lr;
    bool valid = node < N_NODES;
    int arow = w * 16 + lr;
    v8bf afrag[4];
#pragma unroll
    for (int kb = 0; kb < 4; kb++)
        afrag[kb] = *(v8bf*)(&As[arow][((kb * 4 + lg) ^ (arow & 7)) * 8]);

    for (int s = 0; s < 6; s++) {
        int mat = s >> 1;                 // 0=fc_w0, 1=fc_w1, 2=skip_w
        int j0 = (s & 1) * 64;
        const unsigned short* wmat = wb + (size_t)mat * 16384 + j0 * HID;
        __syncthreads();                  // prior slice's Bs reads complete
#pragma unroll
        for (int i = 0; i < 4; i++) {
            int idx = tid * 4 + i;
            int row = idx >> 4, seg = idx & 15;
            uint4 wv = *(const uint4*)(wmat + row * HID + seg * 8);
            *(uint4*)(&Bs[row][(seg ^ (row & 7)) * 8]) = wv;
        }
        __syncthreads();

        // SWAPPED: acc[nt] = W_frag x X_frag -> D[col][node]
        v4f acc[4] = {};
#pragma unroll
        for (int nt = 0; nt < 4; nt++) {
            int brow = nt * 16 + lr;
#pragma unroll
            for (int kb = 0; kb < 4; kb++) {
                v8bf bfrag =
                    *(v8bf*)(&Bs[brow][((kb * 4 + lg) ^ (brow & 7)) * 8]);
                acc[nt] = __builtin_amdgcn_mfma_f32_16x16x32_bf16(
                    bfrag, afrag[kb], acc[nt], 0, 0, 0);
            }
        }

        if (mat < 2) {
            int h = s & 1;
            const float* al = mat ? al1 : al0;
            const float* ar = mat ? ar1 : ar0;
            float* elp = mat ? el1 : el0;
            float* erp = mat ? er1 : er0;
            unsigned short* fbp = mat ? fb1 : fb0;
            float elv = 0.f, erv = 0.f;
#pragma unroll
            for (int nt = 0; nt < 4; nt++) {
                int c0 = j0 + nt * 16 + lg * 4;
                float4 av = *(const float4*)(al + c0);
                float4 rv = *(const float4*)(ar + c0);
                elv += acc[nt][0] * av.x + acc[nt][1] * av.y +
                       acc[nt][2] * av.z + acc[nt][3] * av.w;
                erv += acc[nt][0] * rv.x + acc[nt][1] * rv.y +
                       acc[nt][2] * rv.z + acc[nt][3] * rv.w;
            }
            elv += __shfl_xor(elv, 16);
            elv += __shfl_xor(elv, 32);
            erv += __shfl_xor(erv, 16);
            erv += __shfl_xor(erv, 32);
            if (valid) {
#pragma unroll
                for (int nt = 0; nt < 4; nt++) {
                    uint2 o;
                    o.x = pack2bf(acc[nt][0], acc[nt][1]);
                    o.y = pack2bf(acc[nt][2], acc[nt][3]);
                    *(uint2*)(fbp + (size_t)node * HID + j0 + nt * 16 + lg * 4) = o;
                }
                if (lg == 0) {
                    elp[node * 2 + h] = elv;
                    erp[node * 2 + h] = erv;
                }
            }
        } else if (valid) {
#pragma unroll
            for (int nt = 0; nt < 4; nt++) {
                int c0 = j0 + nt * 16 + lg * 4;
                float4 sb = *(const float4*)(skip_b + c0);
                float4 o;
                o.x = acc[nt][0] + sb.x;
                o.y = acc[nt][1] + sb.y;
                o.z = acc[nt][2] + sb.z;
                o.w = acc[nt][3] + sb.w;
                *(float4*)(hs + (size_t)node * HID + c0) = o;
            }
        }
    }
}

// ---------------------------------------------------------------------------
// CSR pass D: per (rel,bin): LDS histogram -> scan -> offs (+sentinel) ->
// place 8B records (srcByteOff, bf16 (ex*ew) pair) sorted by dst, AND
// accumulate den[node][head] = sum(ex) in f32 LDS -> den2 table.
// grid: (NBINS, 2)
// ---------------------------------------------------------------------------
__global__ __launch_bounds__(256) void k_csr(const int* __restrict__ bincnt,
                                             const int2* __restrict__ pairs0,
                                             const int2* __restrict__ pairs1,
                                             const float* __restrict__ el0,
                                             const float* __restrict__ er0,
                                             const float* __restrict__ el1,
                                             const float* __restrict__ er1,
                                             int* __restrict__ offs0,
                                             int* __restrict__ offs1,
                                             int2* __restrict__ rec0,
                                             int2* __restrict__ rec1,
                                             float2* __restrict__ den20,
                                             float2* __restrict__ den21) {
    int rel = blockIdx.y;
    const int2* pairs = rel ? pairs1 : pairs0;
    const float* el = rel ? el1 : el0;
    const float* er = rel ? er1 : er0;
    int* offs = rel ? offs1 : offs0;
    int2* rec = rel ? rec1 : rec0;
    float2* den2 = rel ? den21 : den20;
    int bin = blockIdx.x;
    int tid = threadIdx.x;
    const int* bc = bincnt + rel * NBINS * NBLK;
    int pbase = bc[bin * NBLK];
    int pend = (bin < NBINS - 1) ? bc[(bin + 1) * NBLK] : N_EDGES;
    int n0 = bin << BINSH;
    int nn = min(N_NODES - n0, BINSZ);

    __shared__ int s_deg[BINSZ];
    __shared__ int s_ts[256];
    __shared__ float sden[BINSZ * 2];
    for (int i = tid; i < BINSZ; i += 256) s_deg[i] = 0;
    for (int i = tid; i < BINSZ * 2; i += 256) sden[i] = 0.f;
    __syncthreads();
    for (int p = pbase + tid; p < pend; p += 256)
        atomicAdd(&s_deg[((unsigned int)pairs[p].x) & (BINSZ - 1)], 1);
    __syncthreads();

    int d0 = s_deg[tid * 2], d1 = s_deg[tid * 2 + 1];
    s_ts[tid] = d0 + d1;
    __syncthreads();
    for (int ofs = 1; ofs < 256; ofs <<= 1) {
        int v = (tid >= ofs) ? s_ts[tid - ofs] : 0;
        __syncthreads();
        s_ts[tid] += v;
        __syncthreads();
    }
    int pre = tid ? s_ts[tid - 1] : 0;
    s_deg[tid * 2] = pbase + pre;
    s_deg[tid * 2 + 1] = pbase + pre + d0;
    __syncthreads();

    for (int l = tid; l < nn; l += 256) offs[n0 + l] = s_deg[l];
    if (bin == NBINS - 1 && tid == 0) offs[N_NODES] = N_EDGES;
    __syncthreads();

    for (int p = pbase + tid; p < pend; p += 256) {
        int2 pr = pairs[p];
        unsigned int u = (unsigned int)pr.x;
        int dl = (int)(u & (BINSZ - 1));
        int s = (int)(u >> BINSH);
        int pos = atomicAdd(&s_deg[dl], 1);
        float2 ev = *(const float2*)(el + 2 * s);
        float2 rv = *(const float2*)(er + 2 * (n0 + dl));
        float x0 = expf(leaky(ev.x + rv.x));
        float x1 = expf(leaky(ev.y + rv.y));
        atomicAdd(&sden[dl * 2], x0);
        atomicAdd(&sden[dl * 2 + 1], x1);
        float ew = __int_as_float(pr.y);
        rec[pos] = make_int2(s << 8, (int)pack2bf(x0 * ew, x1 * ew));
    }
    __syncthreads();
    for (int l = tid; l < nn; l += 256)
        den2[n0 + l] = make_float2(sden[l * 2], sden[l * 2 + 1]);
}

// ---------------------------------------------------------------------------
// K_aggregate: wave per dst node, single pass (den precomputed). 4 edges in
// flight, 16 lanes/edge, unroll 4 for deeper MLP. h updated in place.
// ---------------------------------------------------------------------------
__device__ __forceinline__ void agg_rel2(const int* __restrict__ offs,
                                         const int2* __restrict__ rec,
                                         const float2* __restrict__ den2,
                                         const unsigned char* __restrict__ fbb,
                                         int n, int lane, int sub,
                                         int hh, float* a) {
    int b = offs[n];
    int e_end = offs[n + 1];
    int deg = e_end - b;
    if (deg <= 0) return;
    float2 dn = den2[n];
    float inv0 = 1.f / dn.x, inv1 = 1.f / dn.y;

    int nchunk = (deg + 63) >> 6;
    for (int ch = 0; ch < nchunk; ch++) {
        int p = b + (ch << 6) + lane;
        int s = 0;
        unsigned int wpk = 0;
        if (p < e_end) {
            int2 r = rec[p];
            s = r.x;
            wpk = (unsigned int)r.y;
        }
        unsigned int pk = pack2bf(__uint_as_float(wpk << 16) * inv0,
                                  __uint_as_float(wpk & 0xffff0000u) * inv1);
        int cnt = deg - (ch << 6);
        if (cnt > 64) cnt = 64;
        int ng = (cnt + 3) >> 2;
#pragma unroll 4
        for (int g = 0; g < ng; g++) {
            int sl = (g << 2) + sub;
            int sj = __shfl(s, sl);                      // byte offset
            unsigned int pkj = (unsigned int)__shfl((int)pk, sl);
            float aj = __uint_as_float(hh ? (pkj & 0xffff0000u) : (pkj << 16));
            uint4 fv = *(const uint4*)(fbb + sj);
            a[0] += aj * __uint_as_float(fv.x << 16);
            a[1] += aj * __uint_as_float(fv.x & 0xffff0000u);
            a[2] += aj * __uint_as_float(fv.y << 16);
            a[3] += aj * __uint_as_float(fv.y & 0xffff0000u);
            a[4] += aj * __uint_as_float(fv.z << 16);
            a[5] += aj * __uint_as_float(fv.z & 0xffff0000u);
            a[6] += aj * __uint_as_float(fv.w << 16);
            a[7] += aj * __uint_as_float(fv.w & 0xffff0000u);
        }
    }
}

__global__ __launch_bounds__(256) void k_aggregate(
    const int* __restrict__ offs0, const int2* __restrict__ rec0,
    const float2* __restrict__ den20, const unsigned short* __restrict__ fb0,
    const int* __restrict__ offs1, const int2* __restrict__ rec1,
    const float2* __restrict__ den21, const unsigned short* __restrict__ fb1,
    const float* __restrict__ bias0, const float* __restrict__ bias1,
    float* __restrict__ h) {
    int wave = threadIdx.x >> 6, lane = threadIdx.x & 63;
    int n = blockIdx.x * 4 + wave;
    if (n >= N_NODES) return;
    int cb = lane & 15;        // col block: cols cb*8 .. cb*8+7
    int sub = lane >> 4;       // sub-edge slot (4 edges in flight)
    int hh = cb >> 3;          // head of these cols
    float a[8] = {0.f, 0.f, 0.f, 0.f, 0.f, 0.f, 0.f, 0.f};
    const unsigned char* fbb0 = (const unsigned char*)fb0 + cb * 16;
    const unsigned char* fbb1 = (const unsigned char*)fb1 + cb * 16;
    agg_rel2(offs0, rec0, den20, fbb0, n, lane, sub, hh, a);
    agg_rel2(offs1, rec1, den21, fbb1, n, lane, sub, hh, a);
#pragma unroll
    for (int j = 0; j < 8; j++) {
        a[j] += __shfl_xor(a[j], 16);
        a[j] += __shfl_xor(a[j], 32);
    }
    if (sub == 0) {
        size_t base = (size_t)n * HID + cb * 8;
        float4 v0 = *(const float4*)(h + base);
        float4 v1 = *(const float4*)(h + base + 4);
        int c0 = cb * 8;
        float4 o0, o1;
        o0.x = v0.x + fmaxf(a[0] + bias0[c0 + 0] + bias1[c0 + 0], 0.f);
        o0.y = v0.y + fmaxf(a[1] + bias0[c0 + 1] + bias1[c0 + 1], 0.f);
        o0.z = v0.z + fmaxf(a[2] + bias0[c0 + 2] + bias1[c0 + 2], 0.f);
        o0.w = v0.w + fmaxf(a[3] + bias0[c0 + 3] + bias1[c0 + 3], 0.f);
        o1.x = v1.x + fmaxf(a[4] + bias0[c0 + 4] + bias1[c0 + 4], 0.f);
        o1.y = v1.y + fmaxf(a[5] + bias0[c0 + 5] + bias1[c0 + 5], 0.f);
        o1.z = v1.z + fmaxf(a[6] + bias0[c0 + 6] + bias1[c0 + 6], 0.f);
        o1.w = v1.w + fmaxf(a[7] + bias0[c0 + 7] + bias1[c0 + 7], 0.f);
        *(float4*)(h + base) = o0;
        *(float4*)(h + base + 4) = o1;
    }
}

// ---------------------------------------------------------------------------
// K_bnstats: per-column partial sums over h (float4 loads).
// EXACTLY 512 blocks x 256 threads.
// ---------------------------------------------------------------------------
__global__ __launch_bounds__(256) void k_bnstats(const float* __restrict__ h,
                                                 double* __restrict__ psum,
                                                 double* __restrict__ psumsq) {
    int tid = threadIdx.x;
    const float4* h4 = (const float4*)h;
    double s[4] = {0.0, 0.0, 0.0, 0.0};
    double q[4] = {0.0, 0.0, 0.0, 0.0};
    const int totalv = N_NODES * HID / 4;         // 1.6M float4s
    const int stride = 512 * 256;                 // multiple of 32: cols fixed
    for (int i = blockIdx.x * 256 + tid; i < totalv; i += stride) {
        float4 v = h4[i];
        s[0] += v.x; q[0] += (double)v.x * v.x;
        s[1] += v.y; q[1] += (double)v.y * v.y;
        s[2] += v.z; q[2] += (double)v.z * v.z;
        s[3] += v.w; q[3] += (double)v.w * v.w;
    }
    __shared__ double ls[256][4], lq[256][4];
#pragma unroll
    for (int j = 0; j < 4; j++) {
        ls[tid][j] = s[j];
        lq[tid][j] = q[j];
    }
    __syncthreads();
    if (tid < 32) {                                // col quad = tid*4 + j
#pragma unroll
        for (int j = 0; j < 4; j++) {
            double ss = 0.0, qq = 0.0;
            for (int t = tid; t < 256; t += 32) {
                ss += ls[t][j];
                qq += lq[t][j];
            }
            psum[blockIdx.x * 128 + tid * 4 + j] = ss;
            psumsq[blockIdx.x * 128 + tid * 4 + j] = qq;
        }
    }
}

__global__ void k_bn_finalize(const double* __restrict__ psum,
                              const double* __restrict__ psumsq,
                              const float* __restrict__ gamma,
                              const float* __restrict__ beta,
                              float* __restrict__ ss) {
    int c = threadIdx.x;
    double s = 0.0, q = 0.0;
    for (int b = 0; b < 512; b++) {
        s += psum[b * 128 + c];
        q += psumsq[b * 128 + c];
    }
    double mu = s / N_NODES;
    double var = q / N_NODES - mu * mu;
    float sc = gamma[c] * (float)(1.0 / sqrt(var + (double)BN_EPS));
    ss[c] = sc;
    ss[128 + c] = beta[c] - (float)mu * sc;
}

// ---------------------------------------------------------------------------
// K_classify: MFMA 16x16x32, swapped: D[class][node]; lane holds 4 consecutive
// classes of one node -> single float4 store. grid 782 x 4 waves.
// ---------------------------------------------------------------------------
__global__ __launch_bounds__(256) void k_classify(const float* __restrict__ h,
                                                  const float* __restrict__ ss,
                                                  const float* __restrict__ clf_w,
                                                  const float* __restrict__ clf_b,
                                                  float* __restrict__ out) {
    int w = threadIdx.x >> 6, l = threadIdx.x & 63;
    int lr = l & 15, lg = l >> 4;
    int n0 = (blockIdx.x * 4 + w) * 16;
    if (n0 >= N_NODES) return;

    v8bf afrag[4], bfrag[4];
#pragma unroll
    for (int kb = 0; kb < 4; kb++) {
        int k0 = kb * 32 + lg * 8;
        const float* bp = clf_w + lr * HID + k0;    // class lr weights
        float4 b0 = *(const float4*)bp;
        float4 b1 = *(const float4*)(bp + 4);
        bfrag[kb][0] = (__bf16)b0.x; bfrag[kb][1] = (__bf16)b0.y;
        bfrag[kb][2] = (__bf16)b0.z; bfrag[kb][3] = (__bf16)b0.w;
        bfrag[kb][4] = (__bf16)b1.x; bfrag[kb][5] = (__bf16)b1.y;
        bfrag[kb][6] = (__bf16)b1.z; bfrag[kb][7] = (__bf16)b1.w;
        const float* ap = h + (size_t)(n0 + lr) * HID + k0;  // node lr
        float4 a0 = *(const float4*)ap;
        float4 a1 = *(const float4*)(ap + 4);
        float4 sc0 = *(const float4*)(ss + k0);
        float4 sc1 = *(const float4*)(ss + k0 + 4);
        float4 sh0 = *(const float4*)(ss + 128 + k0);
        float4 sh1 = *(const float4*)(ss + 128 + k0 + 4);
        afrag[kb][0] = (__bf16)fmaxf(a0.x * sc0.x + sh0.x, 0.f);
        afrag[kb][1] = (__bf16)fmaxf(a0.y * sc0.y + sh0.y, 0.f);
        afrag[kb][2] = (__bf16)fmaxf(a0.z * sc0.z + sh0.z, 0.f);
        afrag[kb][3] = (__bf16)fmaxf(a0.w * sc0.w + sh0.w, 0.f);
        afrag[kb][4] = (__bf16)fmaxf(a1.x * sc1.x + sh1.x, 0.f);
        afrag[kb][5] = (__bf16)fmaxf(a1.y * sc1.y + sh1.y, 0.f);
        afrag[kb][6] = (__bf16)fmaxf(a1.z * sc1.z + sh1.z, 0.f);
        afrag[kb][7] = (__bf16)fmaxf(a1.w * sc1.w + sh1.w, 0.f);
    }
    // SWAPPED: D[class][node]; lane holds classes lg*4+r of node n0+lr
    v4f acc = {};
#pragma unroll
    for (int kb = 0; kb < 4; kb++)
        acc = __builtin_amdgcn_mfma_f32_16x16x32_bf16(bfrag[kb], afrag[kb],
                                                      acc, 0, 0, 0);
    float4 cb = *(const float4*)(clf_b + lg * 4);
    float4 o;
    o.x = acc[0] + cb.x;
    o.y = acc[1] + cb.y;
    o.z = acc[2] + cb.z;
    o.w = acc[3] + cb.w;
    *(float4*)(out + (size_t)(n0 + lr) * 16 + lg * 4) = o;
}

// ---------------------------------------------------------------------------
extern "C" void kernel_launch(void* const* d_in, const int* in_sizes, int n_in,
                              void* d_out, int out_size, void* d_ws, size_t ws_size,
                              hipStream_t stream) {
    (void)in_sizes; (void)n_in; (void)out_size; (void)ws_size;
    const float* x      = (const float*)d_in[0];
    const int*   src0   = (const int*)d_in[1];
    const int*   dst0   = (const int*)d_in[2];
    const float* ew0    = (const float*)d_in[3];
    const int*   src1   = (const int*)d_in[4];
    const int*   dst1   = (const int*)d_in[5];
    const float* ew1    = (const float*)d_in[6];
    const float* fc_w0  = (const float*)d_in[7];
    const float* bias0  = (const float*)d_in[8];
    const float* al0    = (const float*)d_in[9];
    const float* ar0    = (const float*)d_in[10];
    const float* fc_w1  = (const float*)d_in[11];
    const float* bias1  = (const float*)d_in[12];
    const float* al1    = (const float*)d_in[13];
    const float* ar1    = (const float*)d_in[14];
    const float* skip_w = (const float*)d_in[15];
    const float* skip_b = (const float*)d_in[16];
    const float* gamma  = (const float*)d_in[17];
    const float* beta   = (const float*)d_in[18];
    const float* clf_w  = (const float*)d_in[19];
    const float* clf_b  = (const float*)d_in[20];
    float* out = (float*)d_out;

    char* wsp = (char*)d_ws;
    size_t off = 0;
    auto alloc = [&](size_t bytes) -> char* {
        char* p = wsp + off;
        off += (bytes + 255) & ~(size_t)255;
        return p;
    };
    unsigned short* wbf = (unsigned short*)alloc((size_t)3 * 16384 * 2);
    unsigned short* fb0 = (unsigned short*)alloc((size_t)N_NODES * HID * 2);
    unsigned short* fb1 = (unsigned short*)alloc((size_t)N_NODES * HID * 2);
    float*  hs     = (float*)alloc((size_t)N_NODES * HID * 4);   // becomes h
    float*  el0    = (float*)alloc((size_t)N_NODES * 2 * 4);
    float*  er0    = (float*)alloc((size_t)N_NODES * 2 * 4);
    float*  el1    = (float*)alloc((size_t)N_NODES * 2 * 4);
    float*  er1    = (float*)alloc((size_t)N_NODES * 2 * 4);
    int*    bincnt = (int*)alloc((size_t)2 * NBINS * NBLK * 4);
    int2*   pairs0 = (int2*)alloc((size_t)N_EDGES * 8);
    int2*   pairs1 = (int2*)alloc((size_t)N_EDGES * 8);
    int*    offs0  = (int*)alloc((size_t)(N_NODES + 1) * 4);
    int*    offs1  = (int*)alloc((size_t)(N_NODES + 1) * 4);
    int2*   rec0   = (int2*)alloc((size_t)N_EDGES * 8);
    int2*   rec1   = (int2*)alloc((size_t)N_EDGES * 8);
    float2* den20  = (float2*)alloc((size_t)N_NODES * 8);
    float2* den21  = (float2*)alloc((size_t)N_NODES * 8);
    double* psum   = (double*)alloc((size_t)512 * 128 * 8);
    double* psumsq = (double*)alloc((size_t)512 * 128 * 8);
    float*  ss     = (float*)alloc(256 * 4);

    // fused: dst-bin histogram (512 blocks) + weight bf16 conversion (48)
    k_prep_count<<<2 * NBLK + 48, 256, 0, stream>>>(fc_w0, fc_w1, skip_w, wbf,
                                                    dst0, dst1, bincnt);
    k_binscan<<<2, 1024, 0, stream>>>(bincnt);

    // fused: binscatter (512 blocks) CONCURRENT with MFMA GEMM (782 blocks)
    k_scatter_gemm<<<2 * NBLK + GEMM_BLOCKS, 256, 0, stream>>>(
        dst0, dst1, src0, src1, ew0, ew1, bincnt, pairs0, pairs1,
        x, wbf, skip_b, al0, ar0, al1, ar1,
        fb0, fb1, el0, er0, el1, er1, hs);

    // CSR finalize: 8B records (ex*ew bf16) + f32 per-node denominators
    dim3 gcsr(NBINS, 2);
    k_csr<<<gcsr, 256, 0, stream>>>(bincnt, pairs0, pairs1,
                                    el0, er0, el1, er1,
                                    offs0, offs1, rec0, rec1, den20, den21);

    // gather aggregation (single pass), h = hs + relu(bias + msgs) in place
    k_aggregate<<<(N_NODES + 3) / 4, 256, 0, stream>>>(
        offs0, rec0, den20, fb0, offs1, rec1, den21, fb1, bias0, bias1, hs);

    k_bnstats<<<512, 256, 0, stream>>>(hs, psum, psumsq);
    k_bn_finalize<<<1, 128, 0, stream>>>(psum, psumsq, gamma, beta, ss);
    k_classify<<<(N_NODES + 63) / 64, 256, 0, stream>>>(
        hs, ss, clf_w, clf_b, out);
}